// Round 6
// baseline (208.579 us; speedup 1.0000x reference)
//
#include <hip/hip_runtime.h>

#define EPSL 1e-9f
#define NG 638976                    // 8192*26*3 groups of 31 floats
#define GPT 3                        // groups per thread
#define TTHREADS (NG / GPT)          // 212992 threads, exact
#define NBLOCKS (TTHREADS / 256)     // 832 blocks x 256 thr = 13 waves/CU
#define NSLOTS 64

// Direct lane-local streaming: NO LDS, no DMA, no waitcnt chains.
// Evidence (r5): fully-cache-warm dispatches ran at the same 66us as cold
// ones -> the old LDS-transpose structure, not HBM, was the wall.
// Each lane loads its own 31-float group via 8-9 ALIGNED float4 from the
// 16B-rounded window (<=12B over-read, absorbed by L1; neighbors use it).
// Alignment residue r=(3g)&3 is static per lane (g == tid mod 4), so a
// 4-way quarter-wave branch keeps all float4-component accesses
// compile-time constant (rule #20: no dynamic indexing -> no scratch).

// compile-time float4 component select (folds: c is a constant expression)
#define C4(v, c) ((c) == 0 ? (v).x : (c) == 1 ? (v).y : (c) == 2 ? (v).z : (v).w)

__global__ __launch_bounds__(256) void laneline_reduce_kernel(
    const float* __restrict__ pred,
    const float* __restrict__ gt,
    float* __restrict__ ws)
{
    const int gtid = blockIdx.x * 256 + threadIdx.x;
    float s0 = 0.f, s1 = 0.f, s2 = 0.f;

// One residue-specialized body: R = (3g)&3, NQ = ceil((R+31)/4) float4 loads.
// Group float j lives at qp[(R+j)>>2] component (R+j)&3 - all constants.
#define BODY(R, NQ) do { \
    _Pragma("unroll") \
    for (int k = 0; k < GPT; ++k) { \
        const size_t g = (size_t)gtid + (size_t)k * TTHREADS; \
        const float4* P4 = (const float4*)(pred + (g * 31 - (R))); \
        const float4* G4 = (const float4*)(gt   + (g * 31 - (R))); \
        float4 qp[NQ], qg[NQ]; \
        _Pragma("unroll") \
        for (int q = 0; q < (NQ); ++q) { qp[q] = P4[q]; qg[q] = G4[q]; } \
        const float gcls = C4(qg[((R) + 30) >> 2], ((R) + 30) & 3); \
        _Pragma("unroll") \
        for (int i = 0; i < 10; ++i) { \
            const float gvis = C4(qg[((R) + 20 + i) >> 2], ((R) + 20 + i) & 3); \
            /* gt ~ U[0,1): gcls*gvis >= 0 so |w*(p-g)| = w*|p-g| */ \
            s2 += gcls * gvis * ( \
                  fabsf(C4(qp[((R) + i) >> 2], ((R) + i) & 3) \
                      - C4(qg[((R) + i) >> 2], ((R) + i) & 3)) \
                + fabsf(C4(qp[((R) + 10 + i) >> 2], ((R) + 10 + i) & 3) \
                      - C4(qg[((R) + 10 + i) >> 2], ((R) + 10 + i) & 3))); \
            const float pv = C4(qp[((R) + 20 + i) >> 2], ((R) + 20 + i) & 3); \
            s0 += gvis * __logf(pv + EPSL) \
                + (1.0f - gvis + EPSL) * __logf(1.0f - pv + EPSL); \
        } \
        const float pc = C4(qp[((R) + 30) >> 2], ((R) + 30) & 3); \
        s1 += gcls * __logf(pc + EPSL) \
            + (1.0f - gcls) * __logf(1.0f - pc + EPSL); \
    } \
} while (0)

    // g mod 4 == tid mod 4 (TTHREADS and block*256 are multiples of 4).
    // residue R = (3g)&3:  g%4: 0->R=0(NQ8), 1->R=3(NQ9), 2->R=2(NQ9), 3->R=1(NQ8)
    // Bounds: max end = g*31 - R + NQ*16 bytes; worst case (last g==3 mod 4
    // group, R=1,NQ=8) ends exactly at NG*31 floats - in bounds.
    const int rsel = threadIdx.x & 3;
    if      (rsel == 0) BODY(0, 8);
    else if (rsel == 1) BODY(3, 9);
    else if (rsel == 2) BODY(2, 9);
    else                BODY(1, 8);

#undef BODY

    // ---- wave shuffle reduction, one atomic triple per wave ----
#pragma unroll
    for (int off = 32; off > 0; off >>= 1) {
        s0 += __shfl_down(s0, off, 64);
        s1 += __shfl_down(s1, off, 64);
        s2 += __shfl_down(s2, off, 64);
    }
    if ((threadIdx.x & 63) == 0) {
        float* slot = ws + ((gtid >> 6) & (NSLOTS - 1)) * 16;  // 64 B stride
        atomicAdd(&slot[0], s0);
        atomicAdd(&slot[1], s1);
        atomicAdd(&slot[2], s2);
    }
}

__global__ __launch_bounds__(64) void laneline_finalize_kernel(
    const float* __restrict__ ws, float* __restrict__ out)
{
    const int t = threadIdx.x;
    float v0 = ws[t * 16], v1 = ws[t * 16 + 1], v2 = ws[t * 16 + 2];
#pragma unroll
    for (int off = 32; off > 0; off >>= 1) {
        v0 += __shfl_down(v0, off, 64);
        v1 += __shfl_down(v1, off, 64);
        v2 += __shfl_down(v2, off, 64);
    }
    if (t == 0) {
        const float l0 = -v0 * 0.1f;   // / NUM_Y_STEPS, negated
        const float l1 = -v1;
        const float l2 =  v2;
        out[0] = l0 + l1 + l2;
        out[1] = l0;
        out[2] = l1;
        out[3] = l2;
    }
}

extern "C" void kernel_launch(void* const* d_in, const int* in_sizes, int n_in,
                              void* d_out, int out_size, void* d_ws, size_t ws_size,
                              hipStream_t stream)
{
    const float* pred = (const float*)d_in[0];
    const float* gt   = (const float*)d_in[1];
    // d_in[2..5] (hcam/pitch) are unused by the reference computation.
    float* ws  = (float*)d_ws;
    float* out = (float*)d_out;

    hipMemsetAsync(ws, 0, NSLOTS * 16 * sizeof(float), stream);

    laneline_reduce_kernel<<<NBLOCKS, 256, 0, stream>>>(pred, gt, ws);
    laneline_finalize_kernel<<<1, 64, 0, stream>>>(ws, out);
}

// Round 8
// 192.529 us; speedup vs baseline: 1.0834x; 1.0834x over previous
//
#include <hip/hip_runtime.h>

#define EPSL 1e-9f
#define NG 638976                    // 8192*26*3 groups of 31 floats
#define NBLOCKS (NG / 256)           // 2496 blocks x 256 thr: 1 group/thread
#define NSLOTS 64

// Direct lane-local streaming, wave-uniform-residue edition.
// r6 evidence: direct float4 loads move the most HBM (1.9 TB/s raw) but
// (a) grid starved occupancy (3.25 blk/CU) and (b) the residue branch was
// LANE-divergent -> every wave ran all 4 bodies at 1/4 EXEC (x4 VALU, x4
// VMEM issue). Fixes: 1 group/thread (2496 blocks, 39 waves/CU supply),
// and group remap g = 4*((w>>2)*64 + lane) + (w&3): bijective, and every
// lane in a wave shares g%4 -> residue branch is SCALAR (readfirstlane),
// one body per wave at full EXEC. No LDS, no DMA; 16B-aligned float4
// windows (<=12B over-read absorbed by L1); all component indices are
// compile-time constants (rule #20: no dynamic reg indexing, no scratch).

// compile-time float4 component select (folds: c is a constant expression)
#define C4(v, c) ((c) == 0 ? (v).x : (c) == 1 ? (v).y : (c) == 2 ? (v).z : (v).w)

__global__ __launch_bounds__(256) void laneline_reduce_kernel(
    const float* __restrict__ pred,
    const float* __restrict__ gt,
    float* __restrict__ ws)
{
    const int gtid = blockIdx.x * 256 + threadIdx.x;
    const int lane = threadIdx.x & 63;
    const int wave = gtid >> 6;                    // global wave id, 0..9983
    // wave-uniform residue selector (provably scalar -> s_cbranch)
    const int rsel = __builtin_amdgcn_readfirstlane(wave & 3);
    const size_t k = (size_t)(wave >> 2) * 64 + lane;

    float s0 = 0.f, s1 = 0.f, s2 = 0.f;

// Residue-specialized body for group g = 4k + RSEL (so g%4 == RSEL,
// byte-alignment residue R = (3g)&3 = (3*RSEL)&3). NQ float4 loads cover
// the 16B-aligned window [g*31-R, g*31-R+4*NQ). Group float j is
// qp[(R+j)>>2] component (R+j)&3 - all compile-time constants.
#define BODY(RSEL, R, NQ) do { \
    const size_t g = 4 * k + (RSEL); \
    const float4* P4 = (const float4*)(pred + (g * 31 - (R))); \
    const float4* G4 = (const float4*)(gt   + (g * 31 - (R))); \
    float4 qp[NQ], qg[NQ]; \
    _Pragma("unroll") \
    for (int q = 0; q < (NQ); ++q) { qp[q] = P4[q]; qg[q] = G4[q]; } \
    const float gcls = C4(qg[((R) + 30) >> 2], ((R) + 30) & 3); \
    _Pragma("unroll") \
    for (int i = 0; i < 10; ++i) { \
        const float gvis = C4(qg[((R) + 20 + i) >> 2], ((R) + 20 + i) & 3); \
        /* gt ~ U[0,1): gcls*gvis >= 0 so |w*(p-g)| = w*|p-g| */ \
        s2 += gcls * gvis * ( \
              fabsf(C4(qp[((R) + i) >> 2], ((R) + i) & 3) \
                  - C4(qg[((R) + i) >> 2], ((R) + i) & 3)) \
            + fabsf(C4(qp[((R) + 10 + i) >> 2], ((R) + 10 + i) & 3) \
                  - C4(qg[((R) + 10 + i) >> 2], ((R) + 10 + i) & 3))); \
        const float pv = C4(qp[((R) + 20 + i) >> 2], ((R) + 20 + i) & 3); \
        s0 += gvis * __logf(pv + EPSL) \
            + (1.0f - gvis + EPSL) * __logf(1.0f - pv + EPSL); \
    } \
    const float pc = C4(qp[((R) + 30) >> 2], ((R) + 30) & 3); \
    s1 += gcls * __logf(pc + EPSL) \
        + (1.0f - gcls) * __logf(1.0f - pc + EPSL); \
} while (0)

    // g%4 -> (R, NQ): 0->(0,8); 1->(3,9); 2->(2,9); 3->(1,8).
    // Bounds (max k = 159743): g=638972..638975; worst end is rsel=3
    // (g=638975, R=1, NQ=8): window ends exactly at NG*31. All in bounds.
    // Start alignment: g*31-R is divisible by 4 floats (R = 3g mod 4).
    if      (rsel == 0) BODY(0, 0, 8);
    else if (rsel == 1) BODY(1, 3, 9);
    else if (rsel == 2) BODY(2, 2, 9);
    else                BODY(3, 1, 8);

#undef BODY

    // ---- wave shuffle reduction, one atomic triple per wave ----
#pragma unroll
    for (int off = 32; off > 0; off >>= 1) {
        s0 += __shfl_down(s0, off, 64);
        s1 += __shfl_down(s1, off, 64);
        s2 += __shfl_down(s2, off, 64);
    }
    if (lane == 0) {
        float* slot = ws + (wave & (NSLOTS - 1)) * 16;  // 64 B stride
        atomicAdd(&slot[0], s0);   // 9984 waves / 64 slots = 156 adds/slot
        atomicAdd(&slot[1], s1);
        atomicAdd(&slot[2], s2);
    }
}

__global__ __launch_bounds__(64) void laneline_finalize_kernel(
    const float* __restrict__ ws, float* __restrict__ out)
{
    const int t = threadIdx.x;
    float v0 = ws[t * 16], v1 = ws[t * 16 + 1], v2 = ws[t * 16 + 2];
#pragma unroll
    for (int off = 32; off > 0; off >>= 1) {
        v0 += __shfl_down(v0, off, 64);
        v1 += __shfl_down(v1, off, 64);
        v2 += __shfl_down(v2, off, 64);
    }
    if (t == 0) {
        const float l0 = -v0 * 0.1f;   // / NUM_Y_STEPS, negated
        const float l1 = -v1;
        const float l2 =  v2;
        out[0] = l0 + l1 + l2;
        out[1] = l0;
        out[2] = l1;
        out[3] = l2;
    }
}

extern "C" void kernel_launch(void* const* d_in, const int* in_sizes, int n_in,
                              void* d_out, int out_size, void* d_ws, size_t ws_size,
                              hipStream_t stream)
{
    const float* pred = (const float*)d_in[0];
    const float* gt   = (const float*)d_in[1];
    // d_in[2..5] (hcam/pitch) are unused by the reference computation.
    float* ws  = (float*)d_ws;
    float* out = (float*)d_out;

    hipMemsetAsync(ws, 0, NSLOTS * 16 * sizeof(float), stream);

    laneline_reduce_kernel<<<NBLOCKS, 256, 0, stream>>>(pred, gt, ws);
    laneline_finalize_kernel<<<1, 64, 0, stream>>>(ws, out);
}

// Round 9
// 187.914 us; speedup vs baseline: 1.1100x; 1.0246x over previous
//
#include <hip/hip_runtime.h>

#define EPSL 1e-9f
#define NG 638976                     // 8192*26*3 groups of 31 floats
#define HGRP 32                       // groups per half-tile (2 lanes/group)
#define HFLOATS (HGRP * 31)           // 992 floats / tensor / half-tile (3968 B)
#define NHT (NG / HGRP)               // 19968 half-tiles
#define NBLOCKS 1248                  // 128-thread (2-wave) blocks
#define NWAVES (NBLOCKS * 2)          // 2496 waves
#define NT (NHT / NWAVES)             // 8 half-tiles per wave, exact
#define NSLOTS 64

// Persistent DMA pipeline at r0's occupancy.
// r8 calibration: VALU ~12% of cycles; ~88% memory-wait. All structures
// converge to 2.35-2.6 TB/s consumed. Last untried combo: persistent +
// coalesced global_load_lds + counted vmcnt + 10 waves/CU. Half-tiles of
// 32 groups shrink the dbuf footprint to 15872 B/wave -> 31744 B/block ->
// 5 blocks/CU = 10 waves/CU (r0's residency, r3's pipeline). Lane PAIRS
// split each group (5 BCE iters each), halving the per-pass serial chain.
// Banks: pair p reads p*31+5h+i -> bank (i +/- ... - p) mod 32, exactly
// 2 lanes/bank = free (m136). No barriers anywhere (per-wave private LDS).
__device__ __forceinline__ void cp_async16(const float* gsrc, float* ldst) {
    __builtin_amdgcn_global_load_lds(
        (const __attribute__((address_space(1))) void*)(uintptr_t)gsrc,
        (__attribute__((address_space(3))) void*)(uint32_t)(uintptr_t)ldst,
        16, 0, 0);
}

__global__ __launch_bounds__(128) void laneline_reduce_kernel(
    const float* __restrict__ pred,
    const float* __restrict__ gt,
    float* __restrict__ ws)
{
    __shared__ float sp[2][2][HFLOATS];   // [wave][buf][float] 15872 B
    __shared__ float sg[2][2][HFLOATS];   // 15872 B

    const int lane = threadIdx.x & 63;
    const int wid  = threadIdx.x >> 6;
    const int wg   = blockIdx.x * 2 + wid;      // global wave id 0..2495

    // stage one half-tile: exactly 8 wave-level DMA instructions
    // (3 full 1KB rounds + lane<56 partial per tensor)
    auto stage = [&](int b, int H) {
        const float* gp = pred + (size_t)H * HFLOATS + lane * 4;
        const float* gg = gt   + (size_t)H * HFLOATS + lane * 4;
#pragma unroll
        for (int r = 0; r < 3; ++r) {
            cp_async16(gp + r * 256, &sp[wid][b][r * 256]);
            cp_async16(gg + r * 256, &sg[wid][b][r * 256]);
        }
        if (lane < 56) {                        // floats 768..991
            cp_async16(gp + 768, &sp[wid][b][768]);
            cp_async16(gg + 768, &sg[wid][b][768]);
        }
    };

    float s0 = 0.f, s1 = 0.f, s2 = 0.f;
    const int grp  = lane >> 1;                 // group within half-tile
    const int half = lane & 1;                  // 0: i in [0,5), 1: [5,10)

    stage(0, wg);                               // prologue: H0 -> buf 0
#pragma unroll
    for (int h = 0; h < NT; ++h) {              // static buf index (unrolled)
        if (h + 1 < NT) {
            // WAR guard + ordering pin, then prefetch next half-tile and
            // wait ONLY for the current one's 8 DMAs (prefetch in flight).
            asm volatile("s_waitcnt lgkmcnt(0)" ::: "memory");
            stage((h + 1) & 1, wg + (h + 1) * NWAVES);
            asm volatile("s_waitcnt vmcnt(8)" ::: "memory");
        } else {
            asm volatile("s_waitcnt vmcnt(0)" ::: "memory");
        }

        const float* lp = &sp[wid][h & 1][grp * 31];
        const float* lg = &sg[wid][h & 1][grp * 31];

        const float gcls = lg[30];              // pair reads same addr: bcast
#pragma unroll
        for (int i = 0; i < 5; ++i) {
            const int j = half * 5 + i;         // this lane's 5 of 10 terms
            const float gvis = lg[20 + j];
            // gt ~ U[0,1): gcls*gvis >= 0 so |w*(p-g)| = w*|p-g|
            s2 += gcls * gvis * (fabsf(lp[j]      - lg[j])
                               + fabsf(lp[10 + j] - lg[10 + j]));
            const float pv = lp[20 + j];
            s0 += gvis * __logf(pv + EPSL)
                + (1.0f - gvis + EPSL) * __logf(1.0f - pv + EPSL);
        }
        if (half == 0) {                        // one lane of the pair: class
            const float pc = lp[30];
            s1 += gcls * __logf(pc + EPSL)
                + (1.0f - gcls) * __logf(1.0f - pc + EPSL);
        }
    }

    // ---- wave shuffle reduction, one atomic triple per wave ----
#pragma unroll
    for (int off = 32; off > 0; off >>= 1) {
        s0 += __shfl_down(s0, off, 64);
        s1 += __shfl_down(s1, off, 64);
        s2 += __shfl_down(s2, off, 64);
    }
    if (lane == 0) {
        float* slot = ws + (wg & (NSLOTS - 1)) * 16;   // 64 B stride
        atomicAdd(&slot[0], s0);
        atomicAdd(&slot[1], s1);
        atomicAdd(&slot[2], s2);
    }
}

__global__ __launch_bounds__(64) void laneline_finalize_kernel(
    const float* __restrict__ ws, float* __restrict__ out)
{
    const int t = threadIdx.x;
    float v0 = ws[t * 16], v1 = ws[t * 16 + 1], v2 = ws[t * 16 + 2];
#pragma unroll
    for (int off = 32; off > 0; off >>= 1) {
        v0 += __shfl_down(v0, off, 64);
        v1 += __shfl_down(v1, off, 64);
        v2 += __shfl_down(v2, off, 64);
    }
    if (t == 0) {
        const float l0 = -v0 * 0.1f;   // / NUM_Y_STEPS, negated
        const float l1 = -v1;
        const float l2 =  v2;
        out[0] = l0 + l1 + l2;
        out[1] = l0;
        out[2] = l1;
        out[3] = l2;
    }
}

extern "C" void kernel_launch(void* const* d_in, const int* in_sizes, int n_in,
                              void* d_out, int out_size, void* d_ws, size_t ws_size,
                              hipStream_t stream)
{
    const float* pred = (const float*)d_in[0];
    const float* gt   = (const float*)d_in[1];
    // d_in[2..5] (hcam/pitch) are unused by the reference computation.
    float* ws  = (float*)d_ws;
    float* out = (float*)d_out;

    hipMemsetAsync(ws, 0, NSLOTS * 16 * sizeof(float), stream);

    laneline_reduce_kernel<<<NBLOCKS, 128, 0, stream>>>(pred, gt, ws);
    laneline_finalize_kernel<<<1, 64, 0, stream>>>(ws, out);
}